// Round 8
// baseline (106.954 us; speedup 1.0000x reference)
//
#include <hip/hip_runtime.h>

#define S_      4096
#define NROT    32
#define NCHUNK  32768                 // 16-vector chunks (one per (b,s) row)
#define NBLK    2048
#define WPB     4                     // waves per block
#define NWAVE   (NBLK * WPB)          // 8192
#define NITER   (NCHUNK / NWAVE)      // 4 chunks per wave
#define MST     68                    // padded M stride (floats): bank=(4d+e)%32,
                                      // rows 16B-aligned (272 B)

typedef __bf16 bf16x4 __attribute__((ext_vector_type(4)));
typedef __bf16 bf16x8 __attribute__((ext_vector_type(8)));
typedef float  f32x4  __attribute__((ext_vector_type(4)));
typedef unsigned short ushort_t;

// bf16-chunk LDS swizzle (involution on 16B granules): write (4k+lhi)*128+l15*8
// and read l15*128+lhi*16+kt*64 both spread 8 lanes per 4-bank group.
__device__ __forceinline__ int swzb(int a) { return a ^ (((a >> 7) & 7) << 4); }

// Prologue M matrix / fragment buffer / main-loop chunk buffers share one LDS
// allocation (phases separated by barriers).
union Scratch {
    float    M[64][MST];              // 17408 B (prologue scan)
    ushort_t frag[4096];              // 8 KB: 8 bf16 B-fragments x 512
    float    chunk[WPB][512];         // 8 KB: 2 KB bf16 staging per wave
};

// ---------------------------------------------------------------------------
// Fused kernel, single-cohort resident (VGPR<=64, 8 blocks/CU).
// Prologue: rotation_matrix -> M (LDS); wave0 left-applies the 32 Givens
// rotations (lane t owns column t; bank=(4i+t)%32 conflict-free); two-pass
// relayout to pi-permuted bf16 MFMA B-fragments; linear b128 fragment loads.
//   fragment (kt,nt): lane l, elem i <- M[d][e],
//     d = kt*32 + 8*(l>>4) + i;  n = l&15;  e = 8*(n>>1) + 2*nt + (n&1)
// Main loop (per wave, private 2 KB LDS buffer, no barriers): depth-1
// reg-staged stream; f32->bf16 before staging (4x ds_write_b64 + 2x
// ds_read_b128, swizzled conflict-free); 8 MFMAs; RoPE epilogue via
// shfl_xor(1); 4 coalesced non-temporal dwordx4 stores per chunk.
// ---------------------------------------------------------------------------
__global__ __launch_bounds__(256, 8) void rope_fused_kernel(
    const float* __restrict__ x,
    const float* __restrict__ thetas,
    const float* __restrict__ rot_pairs,
    const float* __restrict__ theta_scale,
    const float* __restrict__ rot_matrix,
    const float* __restrict__ inv_freq,
    float* __restrict__ out)
{
    __shared__ __align__(16) Scratch sc;
    __shared__ float trig[NROT][2];

    const int t    = threadIdx.x;
    const int lane = t & 63;
    const int w    = t >> 6;
    const int l15  = lane & 15;
    const int lhi  = lane >> 4;
    const int u    = l15 >> 1;
    const bool even = (lane & 1) == 0;

    const int c0 = blockIdx.x * WPB + w;          // first chunk for this wave

    // ---- issue first chunk's loads immediately (hide under prologue)
    f32x4 q[4];
    {
        const float* xa = x + (size_t)c0 * 1024 + lane * 4;
        #pragma unroll
        for (int k = 0; k < 4; ++k)
            q[k] = *reinterpret_cast<const f32x4*>(xa + k * 256);
    }

    // ---- stage rotation_matrix into LDS M (coalesced b128s)
    {
        const int row = t >> 2, c4 = (t & 3) * 16;
        const float* src = rot_matrix + row * 64 + c4;
        #pragma unroll
        for (int j = 0; j < 4; ++j)
            *reinterpret_cast<f32x4*>(&sc.M[row][c4 + 4 * j]) =
                *reinterpret_cast<const f32x4*>(src + 4 * j);
    }
    if (t < NROT) {
        const float th = thetas[t] * theta_scale[0];
        trig[t][0] = cosf(th);
        trig[t][1] = sinf(th);
    }
    __syncthreads();

    // ---- Givens scan, left-applied in reverse order (wave 0; lane t owns
    //      column t; conflict-free)
    if (t < 64) {
        #pragma unroll
        for (int k = NROT - 1; k >= 0; --k) {
            const int   i = (int)rot_pairs[2 * k];
            const int   j = (int)rot_pairs[2 * k + 1];
            const float c = trig[k][0];
            const float s = trig[k][1];
            const float mi = sc.M[i][t];
            const float mj = sc.M[j][t];
            if (i == j) {
                sc.M[i][t] = c * mi;   // reference's .at chain leaves G[i,i]=c
            } else {
                sc.M[i][t] = fmaf(c, mi, -s * mj);
                sc.M[j][t] = fmaf(s, mi,  c * mj);
            }
        }
    }
    __syncthreads();

    // ---- relayout phase A: gather the 16 M values forming frag entries
    //      F = t*16..t*16+15 (padded stride spreads banks)
    float vals[16];
    #pragma unroll
    for (int m = 0; m < 16; ++m) {
        const int F  = t * 16 + m;
        const int f  = F >> 9;
        const int ln = (F >> 3) & 63;
        const int i  = F & 7;
        const int kt = f >> 2, nt = f & 3;
        const int d  = kt * 32 + 8 * (ln >> 4) + i;
        const int n  = ln & 15;
        const int e  = 8 * (n >> 1) + 2 * nt + (n & 1);
        vals[m] = sc.M[d][e];
    }
    __syncthreads();

    // ---- relayout phase B: pack to bf16, write 32 B linear (2x b128)
    {
        uint32_t dw[8];
        #pragma unroll
        for (int m = 0; m < 8; ++m) {
            union { __bf16 h; ushort_t s; } lo, hi;
            lo.h = (__bf16)vals[2 * m];
            hi.h = (__bf16)vals[2 * m + 1];
            dw[m] = (uint32_t)lo.s | ((uint32_t)hi.s << 16);
        }
        uint32_t* dst = reinterpret_cast<uint32_t*>(sc.frag + t * 16);
        *reinterpret_cast<uint4*>(dst)     = make_uint4(dw[0], dw[1], dw[2], dw[3]);
        *reinterpret_cast<uint4*>(dst + 4) = make_uint4(dw[4], dw[5], dw[6], dw[7]);
    }
    __syncthreads();

    // ---- load the 8 B-fragments (linear, conflict-free)
    bf16x8 bf[2][4];
    #pragma unroll
    for (int kt = 0; kt < 2; ++kt)
        #pragma unroll
        for (int nt = 0; nt < 4; ++nt)
            bf[kt][nt] = *reinterpret_cast<const bf16x8*>(
                sc.frag + ((kt * 4 + nt) * 512 + lane * 8));
    __syncthreads();   // frag region dead; chunk buffers may now be written

    // ---- main-loop constants
    const f32x4 invf = *reinterpret_cast<const f32x4*>(inv_freq + 4 * u);
    const float INV2PI = 0.15915494309189535f;
    char* wbuf = reinterpret_cast<char*>(sc.chunk[w]);

    int wr_off[4];
    #pragma unroll
    for (int k = 0; k < 4; ++k)
        wr_off[k] = swzb((k * 4 + lhi) * 128 + l15 * 8);
    const int rd0 = swzb(l15 * 128 + lhi * 16);
    const int rd1 = swzb(l15 * 128 + lhi * 16 + 64);

    // ---- streaming main loop (depth-1; per-wave LDS, no barriers)
    int c = c0;
    #pragma unroll 1
    for (int it = 0; it < NITER; ++it) {
        // convert f32->bf16 and stage (4x ds_write_b64, swizzled)
        #pragma unroll
        for (int k = 0; k < 4; ++k) {
            bf16x4 h;
            #pragma unroll
            for (int i = 0; i < 4; ++i) h[i] = (__bf16)q[k][i];
            *reinterpret_cast<bf16x4*>(wbuf + wr_off[k]) = h;
        }

        // q dead after staging: issue next chunk's loads now
        if (it + 1 < NITER) {
            const float* xn = x + (size_t)(c + NWAVE) * 1024 + lane * 4;
            #pragma unroll
            for (int k = 0; k < 4; ++k)
                q[k] = *reinterpret_cast<const f32x4*>(xn + k * 256);
        }

        // A fragments from LDS (2x ds_read_b128, conflict-free)
        const bf16x8 a0 = *reinterpret_cast<const bf16x8*>(wbuf + rd0);
        const bf16x8 a1 = *reinterpret_cast<const bf16x8*>(wbuf + rd1);

        f32x4 acc[4];
        #pragma unroll
        for (int nt = 0; nt < 4; ++nt) {
            acc[nt] = (f32x4){0.f, 0.f, 0.f, 0.f};
            acc[nt] = __builtin_amdgcn_mfma_f32_16x16x32_bf16(a0, bf[0][nt], acc[nt], 0, 0, 0);
            acc[nt] = __builtin_amdgcn_mfma_f32_16x16x32_bf16(a1, bf[1][nt], acc[nt], 0, 0, 0);
        }

        // trig: position s uniform over the chunk (chunk = b*4096 + s)
        const int s = c & (S_ - 1);
        float cs[4], sn2[4];
        #pragma unroll
        for (int nt = 0; nt < 4; ++nt) {
            float rev = (float)s * invf[nt] * INV2PI;
            rev -= floorf(rev);
            const float sv = __builtin_amdgcn_sinf(rev);
            cs[nt]  = __builtin_amdgcn_cosf(rev);
            sn2[nt] = even ? -sv : sv;
        }

        // epilogue: pi makes the 4 nt-results contiguous -> coalesced
        // non-temporal dwordx4 stores
        float* outc = out + (size_t)c * 1024;
        #pragma unroll
        for (int j = 0; j < 4; ++j) {
            f32x4 res;
            #pragma unroll
            for (int nt = 0; nt < 4; ++nt) {
                const float own = acc[nt][j];
                const float oth = __shfl_xor(own, 1, 64);
                res[nt] = fmaf(oth, sn2[nt], own * cs[nt]);
            }
            const int row  = lhi * 4 + j;
            const int col0 = (even ? 0 : 32) + 4 * u;
            __builtin_nontemporal_store(
                res, reinterpret_cast<f32x4*>(outc + row * 64 + col0));
        }

        c += NWAVE;
    }
}

// ---------------------------------------------------------------------------
extern "C" void kernel_launch(void* const* d_in, const int* in_sizes, int n_in,
                              void* d_out, int out_size, void* d_ws, size_t ws_size,
                              hipStream_t stream)
{
    const float* x           = (const float*)d_in[0];
    const float* thetas      = (const float*)d_in[1];
    const float* rot_pairs   = (const float*)d_in[2];
    const float* theta_scale = (const float*)d_in[3];
    const float* rot_matrix  = (const float*)d_in[4];
    const float* inv_freq    = (const float*)d_in[5];
    float*       outp        = (float*)d_out;

    rope_fused_kernel<<<NBLK, 256, 0, stream>>>(
        x, thetas, rot_pairs, theta_scale, rot_matrix, inv_freq, outp);
}

// Round 9
// 48.776 us; speedup vs baseline: 2.1928x; 2.1928x over previous
//
#include <hip/hip_runtime.h>

#define S_      4096
#define NROT    32
#define NCHUNK  32768                 // 16-vector chunks (one per (b,s) row)
#define NBLK    1024                  // 4 blocks/CU -> whole grid co-resident
#define WPB     4                     // waves per block
#define NWAVE   (NBLK * WPB)          // 4096
#define NITER   (NCHUNK / NWAVE)      // 8 chunks per wave
#define MST     68                    // padded M stride (floats): bank=(4d+e)%32,
                                      // rows 16B-aligned (272 B)

typedef __bf16 bf16x4 __attribute__((ext_vector_type(4)));
typedef __bf16 bf16x8 __attribute__((ext_vector_type(8)));
typedef float  f32x4  __attribute__((ext_vector_type(4)));
typedef unsigned short ushort_t;

// bf16-chunk LDS swizzle (involution on 16B granules): write (4k+lhi)*128+l15*8
// and read l15*128+lhi*16+kt*64 both spread 8 lanes per 4-bank group.
__device__ __forceinline__ int swzb(int a) { return a ^ (((a >> 7) & 7) << 4); }

// Prologue M matrix / fragment buffer / main-loop chunk buffers share one LDS
// allocation (phases separated by barriers).
union Scratch {
    float    M[64][MST];              // 17408 B (prologue scan)
    ushort_t frag[4096];              // 8 KB: 8 bf16 B-fragments x 512
    float    chunk[WPB][512];         // 8 KB: 2 KB bf16 staging per wave
};

// ---------------------------------------------------------------------------
// Fused kernel, single-cohort grid (1024 blocks = 4 blocks/CU at VGPR~68).
// Prologue: rotation_matrix -> M (LDS); wave0 left-applies the 32 Givens
// rotations (lane t owns column t); two-pass relayout to pi-permuted bf16
// MFMA B-fragments; linear b128 fragment loads.
//   fragment (kt,nt): lane l, elem i <- M[d][e],
//     d = kt*32 + 8*(l>>4) + i;  n = l&15;  e = 8*(n>>1) + 2*nt + (n&1)
// Main loop (per wave, private 2 KB LDS buffer, no barriers): depth-1
// reg-staged stream; f32->bf16 before staging (4x ds_write_b64 + 2x
// ds_read_b128, swizzled conflict-free); 8 MFMAs; RoPE epilogue via
// shfl_xor(1); 4 coalesced non-temporal dwordx4 stores per chunk.
// ---------------------------------------------------------------------------
__global__ __launch_bounds__(256) void rope_fused_kernel(
    const float* __restrict__ x,
    const float* __restrict__ thetas,
    const float* __restrict__ rot_pairs,
    const float* __restrict__ theta_scale,
    const float* __restrict__ rot_matrix,
    const float* __restrict__ inv_freq,
    float* __restrict__ out)
{
    __shared__ __align__(16) Scratch sc;
    __shared__ float trig[NROT][2];
    __shared__ int   ipair[NROT][2];

    const int t    = threadIdx.x;
    const int lane = t & 63;
    const int w    = t >> 6;
    const int l15  = lane & 15;
    const int lhi  = lane >> 4;
    const int u    = l15 >> 1;
    const bool even = (lane & 1) == 0;

    const int c0 = blockIdx.x * WPB + w;          // first chunk for this wave

    // ---- issue first chunk's loads immediately (hide under prologue)
    f32x4 q[4];
    {
        const float* xa = x + (size_t)c0 * 1024 + lane * 4;
        #pragma unroll
        for (int k = 0; k < 4; ++k)
            q[k] = *reinterpret_cast<const f32x4*>(xa + k * 256);
    }

    // ---- stage rotation_matrix into LDS M (coalesced b128s)
    {
        const int row = t >> 2, c4 = (t & 3) * 16;
        const float* src = rot_matrix + row * 64 + c4;
        #pragma unroll
        for (int j = 0; j < 4; ++j)
            *reinterpret_cast<f32x4*>(&sc.M[row][c4 + 4 * j]) =
                *reinterpret_cast<const f32x4*>(src + 4 * j);
    }
    // trig + pair preload (removes global-load latency from the serial scan)
    if (t < NROT) {
        const float th = thetas[t] * theta_scale[0];
        trig[t][0]  = cosf(th);
        trig[t][1]  = sinf(th);
        ipair[t][0] = (int)rot_pairs[2 * t];
        ipair[t][1] = (int)rot_pairs[2 * t + 1];
    }
    __syncthreads();

    // ---- Givens scan, left-applied in reverse order (wave 0; lane t owns
    //      column t; only the M-update chain is serial)
    if (t < 64) {
        #pragma unroll
        for (int k = NROT - 1; k >= 0; --k) {
            const int   i = ipair[k][0];
            const int   j = ipair[k][1];
            const float c = trig[k][0];
            const float s = trig[k][1];
            const float mi = sc.M[i][t];
            const float mj = sc.M[j][t];
            if (i == j) {
                sc.M[i][t] = c * mi;   // reference's .at chain leaves G[i,i]=c
            } else {
                sc.M[i][t] = fmaf(c, mi, -s * mj);
                sc.M[j][t] = fmaf(s, mi,  c * mj);
            }
        }
    }
    __syncthreads();

    // ---- relayout phase A: gather the 16 M values forming frag entries
    //      F = t*16..t*16+15 (padded stride spreads banks)
    float vals[16];
    #pragma unroll
    for (int m = 0; m < 16; ++m) {
        const int F  = t * 16 + m;
        const int f  = F >> 9;
        const int ln = (F >> 3) & 63;
        const int i  = F & 7;
        const int kt = f >> 2, nt = f & 3;
        const int d  = kt * 32 + 8 * (ln >> 4) + i;
        const int n  = ln & 15;
        const int e  = 8 * (n >> 1) + 2 * nt + (n & 1);
        vals[m] = sc.M[d][e];
    }
    __syncthreads();

    // ---- relayout phase B: pack to bf16, write 32 B linear (2x b128)
    {
        uint32_t dw[8];
        #pragma unroll
        for (int m = 0; m < 8; ++m) {
            union { __bf16 h; ushort_t s; } lo, hi;
            lo.h = (__bf16)vals[2 * m];
            hi.h = (__bf16)vals[2 * m + 1];
            dw[m] = (uint32_t)lo.s | ((uint32_t)hi.s << 16);
        }
        uint32_t* dst = reinterpret_cast<uint32_t*>(sc.frag + t * 16);
        *reinterpret_cast<uint4*>(dst)     = make_uint4(dw[0], dw[1], dw[2], dw[3]);
        *reinterpret_cast<uint4*>(dst + 4) = make_uint4(dw[4], dw[5], dw[6], dw[7]);
    }
    __syncthreads();

    // ---- load the 8 B-fragments (linear, conflict-free)
    bf16x8 bf[2][4];
    #pragma unroll
    for (int kt = 0; kt < 2; ++kt)
        #pragma unroll
        for (int nt = 0; nt < 4; ++nt)
            bf[kt][nt] = *reinterpret_cast<const bf16x8*>(
                sc.frag + ((kt * 4 + nt) * 512 + lane * 8));
    __syncthreads();   // frag region dead; chunk buffers may now be written

    // ---- main-loop constants
    const f32x4 invf = *reinterpret_cast<const f32x4*>(inv_freq + 4 * u);
    const float INV2PI = 0.15915494309189535f;
    char* wbuf = reinterpret_cast<char*>(sc.chunk[w]);

    int wr_off[4];
    #pragma unroll
    for (int k = 0; k < 4; ++k)
        wr_off[k] = swzb((k * 4 + lhi) * 128 + l15 * 8);
    const int rd0 = swzb(l15 * 128 + lhi * 16);
    const int rd1 = swzb(l15 * 128 + lhi * 16 + 64);

    // ---- streaming main loop (depth-1; per-wave LDS, no barriers)
    int c = c0;
    #pragma unroll 1
    for (int it = 0; it < NITER; ++it) {
        // convert f32->bf16 and stage (4x ds_write_b64, swizzled)
        #pragma unroll
        for (int k = 0; k < 4; ++k) {
            bf16x4 h;
            #pragma unroll
            for (int i = 0; i < 4; ++i) h[i] = (__bf16)q[k][i];
            *reinterpret_cast<bf16x4*>(wbuf + wr_off[k]) = h;
        }

        // q dead after staging: issue next chunk's loads now
        if (it + 1 < NITER) {
            const float* xn = x + (size_t)(c + NWAVE) * 1024 + lane * 4;
            #pragma unroll
            for (int k = 0; k < 4; ++k)
                q[k] = *reinterpret_cast<const f32x4*>(xn + k * 256);
        }

        // A fragments from LDS (2x ds_read_b128, conflict-free)
        const bf16x8 a0 = *reinterpret_cast<const bf16x8*>(wbuf + rd0);
        const bf16x8 a1 = *reinterpret_cast<const bf16x8*>(wbuf + rd1);

        f32x4 acc[4];
        #pragma unroll
        for (int nt = 0; nt < 4; ++nt) {
            acc[nt] = (f32x4){0.f, 0.f, 0.f, 0.f};
            acc[nt] = __builtin_amdgcn_mfma_f32_16x16x32_bf16(a0, bf[0][nt], acc[nt], 0, 0, 0);
            acc[nt] = __builtin_amdgcn_mfma_f32_16x16x32_bf16(a1, bf[1][nt], acc[nt], 0, 0, 0);
        }

        // trig: position s uniform over the chunk (chunk = b*4096 + s)
        const int s = c & (S_ - 1);
        float cs[4], sn2[4];
        #pragma unroll
        for (int nt = 0; nt < 4; ++nt) {
            float rev = (float)s * invf[nt] * INV2PI;
            rev -= floorf(rev);
            const float sv = __builtin_amdgcn_sinf(rev);
            cs[nt]  = __builtin_amdgcn_cosf(rev);
            sn2[nt] = even ? -sv : sv;
        }

        // epilogue: pi makes the 4 nt-results contiguous -> coalesced
        // non-temporal dwordx4 stores
        float* outc = out + (size_t)c * 1024;
        #pragma unroll
        for (int j = 0; j < 4; ++j) {
            f32x4 res;
            #pragma unroll
            for (int nt = 0; nt < 4; ++nt) {
                const float own = acc[nt][j];
                const float oth = __shfl_xor(own, 1, 64);
                res[nt] = fmaf(oth, sn2[nt], own * cs[nt]);
            }
            const int row  = lhi * 4 + j;
            const int col0 = (even ? 0 : 32) + 4 * u;
            __builtin_nontemporal_store(
                res, reinterpret_cast<f32x4*>(outc + row * 64 + col0));
        }

        c += NWAVE;
    }
}

// ---------------------------------------------------------------------------
extern "C" void kernel_launch(void* const* d_in, const int* in_sizes, int n_in,
                              void* d_out, int out_size, void* d_ws, size_t ws_size,
                              hipStream_t stream)
{
    const float* x           = (const float*)d_in[0];
    const float* thetas      = (const float*)d_in[1];
    const float* rot_pairs   = (const float*)d_in[2];
    const float* theta_scale = (const float*)d_in[3];
    const float* rot_matrix  = (const float*)d_in[4];
    const float* inv_freq    = (const float*)d_in[5];
    float*       outp        = (float*)d_out;

    rope_fused_kernel<<<NBLK, 256, 0, stream>>>(
        x, thetas, rot_pairs, theta_scale, rot_matrix, inv_freq, outp);
}